// Round 13
// baseline (314.739 us; speedup 1.0000x reference)
//
#include <hip/hip_runtime.h>
#include <hip/hip_bf16.h>

#define B_ 4096
#define D_ 1024
#define H_ 8192
#define O_ 1000
#define K2 2048          // physical packed K ([hi|lo])
#define NT 96            // logical K-tiles: 3072 / 32

typedef __attribute__((ext_vector_type(8))) short short8;
typedef __attribute__((ext_vector_type(4))) short short4v;
typedef __attribute__((ext_vector_type(16))) float f32x16;

union BF4 { __hip_bfloat16 b[4]; short4v s; };

__device__ __forceinline__ void gload16(void* ldsp, const void* g) {
  __builtin_amdgcn_global_load_lds(
      (const __attribute__((address_space(1))) unsigned int*)g,
      (__attribute__((address_space(3))) unsigned int*)ldsp, 16, 0, 0);
}

// K-tile T (32 k) -> column offset in packed [hi|lo] rows. bf16x3 interleave
// on 64-k granules g = T>>1: r0 = xh*wh, r1 = xl*wh, r2 = xh*wl.
__device__ __forceinline__ int aoff32_(int T) {
  const int g = T >> 1, t = g / 3, r = g - 3 * t;
  return (r == 1 ? 1024 : 0) + t * 64 + (T & 1) * 32;
}
__device__ __forceinline__ int boff32_(int T) {
  const int g = T >> 1, t = g / 3, r = g - 3 * t;
  return (r == 2 ? 1024 : 0) + t * 64 + (T & 1) * 32;
}

// ---- merged split: fp32 -> [hi|lo] bf16 + sum-of-squares + keys init ----
__global__ __launch_bounds__(256) void split_all_kernel(
    const float* __restrict__ x, const float* __restrict__ w,
    __hip_bfloat16* __restrict__ Ap, __hip_bfloat16* __restrict__ Bp,
    float* __restrict__ xsq, float* __restrict__ wsq,
    unsigned long long* __restrict__ keys)
{
  const int r = blockIdx.x;
  const int t = threadIdx.x;
  const float* src;
  __hip_bfloat16* dst;
  float* sq;
  if (r < B_) {
    src = x + (size_t)r * D_; dst = Ap + (size_t)r * K2; sq = xsq + r;
    if (t == 0) keys[r] = ~0ULL;
  } else {
    const int rr = r - B_;
    src = w + (size_t)rr * D_; dst = Bp + (size_t)rr * K2; sq = wsq + rr;
  }
  const float4 v = ((const float4*)src)[t];
  float ss = v.x * v.x + v.y * v.y + v.z * v.z + v.w * v.w;

  BF4 Hh, Ll;
  const float e[4] = {v.x, v.y, v.z, v.w};
#pragma unroll
  for (int i = 0; i < 4; ++i) {
    __hip_bfloat16 h = __float2bfloat16(e[i]);
    Hh.b[i] = h;
    Ll.b[i] = __float2bfloat16(e[i] - __bfloat162float(h));
  }
  *(short4v*)(dst + t * 4) = Hh.s;
  *(short4v*)(dst + 1024 + t * 4) = Ll.s;

#pragma unroll
  for (int o = 32; o > 0; o >>= 1) ss += __shfl_down(ss, o);
  __shared__ float wsum[4];
  if ((t & 63) == 0) wsum[t >> 6] = ss;
  __syncthreads();
  if (t == 0) *sq = (wsum[0] + wsum[1]) + (wsum[2] + wsum[3]);
}

// ---- 256x128 GEMM, 4 waves/block, 48 KB LDS -> 2 BLOCKS/CU ----
// Occupancy bet, register-legal this time: launch_bounds(256,2) gives a
// 256-reg/wave budget (need ~220 -> NO SPILL; r12's failure was the
// 128-reg budget forcing spills whose flat/scratch ops corrupted the
// hand-counted lgkm ledger).
// Buf b (24 KB) at b*24576: A 256 rows x 32k @ +0 (64B rows),
// B 128 cols x 32k @ +16384. Swizzle: phys 16B-unit = logical ^ f(row),
// f(row) = (row>>3)&3 (r10/r11: conflicts measured 0), applied via
// pre-swizzled global source (linear LDS dst for gload_lds).
// Waves: wid 0..3; wm = wid>>1 (A half), wn = wid&1 (B half); wave tile
// 128x64. Tile T: 12 asm ds_reads (2 kk x 6) + 16 mfma_32x32x16;
// stage tile T+1 (6 gloads) into buf (T+1)&1 — WAR-safe: that buf's reads
// (tile T-1's) lgkm-drained before T-1's trailing barrier.
// Gate vmcnt(0) + barrier at tile end certifies buf(T+1).

#define BAR() do { asm volatile("" ::: "memory"); \
                   __builtin_amdgcn_s_barrier(); \
                   asm volatile("" ::: "memory"); } while (0)
#define SB0() __builtin_amdgcn_sched_barrier(0)
#define GATEV0() asm volatile("s_waitcnt vmcnt(0)" ::: "memory")
#define LGKM6() do { asm volatile("s_waitcnt lgkmcnt(6)"); SB0(); } while (0)
#define LGKM0() do { asm volatile("s_waitcnt lgkmcnt(0)"); SB0(); } while (0)

#define DSR(dst, base, OFF) \
  asm volatile("ds_read_b128 %0, %1 offset:" OFF : "=v"(dst) : "v"(base))

// 6 reads for kk-granule KK: 4 A (m*32 rows) + 2 B (n*32 cols)
#define RDP(F, DSEL, KK) do { \
    const unsigned a_ = aB + (DSEL) + ofk##KK; \
    const unsigned b_ = bB + (DSEL) + ofk##KK; \
    DSR(F[0], a_, "0");    DSR(F[1], a_, "2048"); \
    DSR(F[2], a_, "4096"); DSR(F[3], a_, "6144"); \
    DSR(F[4], b_, "0");    DSR(F[5], b_, "2048"); \
  } while (0)

// Stage tile T: A = 4 gloads (64 rows each), B = 2 gloads; 256 threads,
// thread t covers row g*64 + (t>>2), phys unit t&3 (su pre-swizzled).
#define STAGE_T(T) do { \
    const int ka_ = aoff32_(T); \
    const int kb_ = boff32_(T); \
    char* da_ = lds + ((T)&1)*24576 + t * 16; \
    gload16(da_,         gA0 + ka_); \
    gload16(da_ + 4096,  gA1 + ka_); \
    gload16(da_ + 8192,  gA2 + ka_); \
    gload16(da_ + 12288, gA3 + ka_); \
    gload16(da_ + 16384, gB0 + kb_); \
    gload16(da_ + 20480, gB1 + kb_); } while (0)

#define MFMA32(a, b, c) __builtin_amdgcn_mfma_f32_32x32x16_bf16(a, b, c, 0, 0, 0)

#define MMQ32(F) do { \
    __builtin_amdgcn_s_setprio(1); \
    acc[0][0] = MFMA32(F[0], F[4], acc[0][0]); \
    acc[0][1] = MFMA32(F[0], F[5], acc[0][1]); \
    acc[1][0] = MFMA32(F[1], F[4], acc[1][0]); \
    acc[1][1] = MFMA32(F[1], F[5], acc[1][1]); \
    acc[2][0] = MFMA32(F[2], F[4], acc[2][0]); \
    acc[2][1] = MFMA32(F[2], F[5], acc[2][1]); \
    acc[3][0] = MFMA32(F[3], F[4], acc[3][0]); \
    acc[3][1] = MFMA32(F[3], F[5], acc[3][1]); \
    __builtin_amdgcn_s_setprio(0); \
    SB0(); } while (0)

// One K-tile. DSEL compile-time buf byte offset (0 / 24576).
#define TILE(DSEL, T) do { \
    RDP(f0, DSEL, 0); \
    RDP(f1, DSEL, 1); \
    if ((T) + 1 < NT) STAGE_T((T) + 1); \
    LGKM6(); \
    MMQ32(f0); \
    LGKM0(); \
    MMQ32(f1); \
    GATEV0(); BAR(); \
  } while (0)

__global__ __launch_bounds__(256, 2) void gemm_argmin_kernel(
    const __hip_bfloat16* __restrict__ Ap, const __hip_bfloat16* __restrict__ Bp,
    const float* __restrict__ xsq, const float* __restrict__ wsq,
    unsigned long long* __restrict__ keys)
{
  __shared__ char lds[49152];

  const int t = threadIdx.x;
  // XCD-aware: 1024 blocks, 8 XCDs -> 8x16 tile-chunk per XCD.
  const int id = blockIdx.x;
  const int xcd = id & 7;
  const int r_ = id >> 3;                      // 0..127
  const int by = (xcd >> 2) * 8 + (r_ >> 4);   // 0..15
  const int bx = (xcd & 3) * 16 + (r_ & 15);   // 0..63
  const int brow = by * 256, bcol = bx * 128;

  const int lane = t & 63, wid = t >> 6;       // 4 waves
  const int wm = wid >> 1, wn = wid & 1;       // wave tile 128 rows x 64 cols
  const int c31 = lane & 31;                   // frag row/col
  const int kh = lane >> 5;                    // k-half within 16-k granule
  const unsigned fsw = (unsigned)((c31 >> 3) & 3);  // f(row), row = c31 mod 32

  // swizzled 16B-unit offsets: row has 4 units; kk granule uses 2kk+kh
  const unsigned ofk0 = (((0u + kh) ^ fsw) * 16);
  const unsigned ofk1 = (((2u + kh) ^ fsw) * 16);

  const unsigned lb = (unsigned)(uintptr_t)lds;
  const unsigned aB = lb + (unsigned)(wm * 8192 + c31 * 64);
  const unsigned bB = lb + (unsigned)(16384 + wn * 4096 + c31 * 64);

  // staging source: thread t covers row g*64 + (t>>2), phys unit t&3;
  // f(row) = ((g*64 + (t>>2))>>3)&3 = (t>>5)&3  (g*8 == 0 mod 4)
  const int sr = t >> 2;
  const int su = (t & 3) ^ ((t >> 5) & 3);
  const __hip_bfloat16* gA0 = Ap + (size_t)(brow + sr) * K2 + su * 8;
  const __hip_bfloat16* gA1 = Ap + (size_t)(brow + 64 + sr) * K2 + su * 8;
  const __hip_bfloat16* gA2 = Ap + (size_t)(brow + 128 + sr) * K2 + su * 8;
  const __hip_bfloat16* gA3 = Ap + (size_t)(brow + 192 + sr) * K2 + su * 8;
  const __hip_bfloat16* gB0 = Bp + (size_t)(bcol + sr) * K2 + su * 8;
  const __hip_bfloat16* gB1 = Bp + (size_t)(bcol + 64 + sr) * K2 + su * 8;

  f32x16 acc[4][2] = {};
  short8 f0[6], f1[6];

  // Prologue: stage tile0; certify; enter loop.
  STAGE_T(0);
  GATEV0();
  BAR();

  for (int tt = 0; tt < NT; tt += 2) {
    TILE(0, tt);
    TILE(24576, tt + 1);
  }

  // Epilogue: s = (x_sq - 2*dot) + w_sq (reference fp32 rounding order).
  // 32x32 C/D (m74/m101, r2/r9-r11-validated): col = lane&31,
  // row = (reg&3) + 8*(reg>>2) + 4*(lane>>5).
#pragma unroll
  for (int m = 0; m < 4; ++m) {
#pragma unroll
    for (int rg = 0; rg < 16; ++rg) {
      const int row = brow + wm * 128 + m * 32 + (rg & 3) + 8 * (rg >> 2) + 4 * kh;
      const float xs = xsq[row];
      unsigned long long best = ~0ULL;
#pragma unroll
      for (int n = 0; n < 2; ++n) {
        const int col = bcol + wn * 64 + n * 32 + c31;
        const float s = (xs - 2.0f * acc[m][n][rg]) + wsq[col];
        unsigned ub = __float_as_uint(s);
        ub = (ub & 0x80000000u) ? ~ub : (ub | 0x80000000u);
        const unsigned long long key =
            ((unsigned long long)ub << 32) | (unsigned)col;
        if (key < best) best = key;
      }
#pragma unroll
      for (int o = 1; o < 32; o <<= 1) {   // reduce within each 32-lane half
        const unsigned long long v = __shfl_xor(best, o);
        if (v < best) best = v;
      }
      if (c31 == 0) atomicMin(&keys[row], best);
    }
  }
}

// ---- transpose G [O,H] -> GT [H,O] ----
__global__ __launch_bounds__(256) void transposeG_kernel(
    const float* __restrict__ G, float* __restrict__ GT)
{
  __shared__ float tile[32][33];
  const int h0 = blockIdx.x * 32;
  const int o0 = blockIdx.y * 32;
  const int tx = threadIdx.x;
  const int ty = threadIdx.y;
#pragma unroll
  for (int j = 0; j < 4; ++j) {
    const int o = o0 + ty + j * 8;
    if (o < O_) tile[ty + j * 8][tx] = G[(size_t)o * H_ + h0 + tx];
  }
  __syncthreads();
  const int o = o0 + tx;
  if (o < O_) {
#pragma unroll
    for (int j = 0; j < 4; ++j)
      GT[(size_t)(h0 + ty + j * 8) * O_ + o] = tile[tx][ty + j * 8];
  }
}

// ---- winners + row gather ----
__global__ __launch_bounds__(256) void finalize_kernel(
    const unsigned long long* __restrict__ keys,
    const float* __restrict__ GT, float* __restrict__ out)
{
  const int b = blockIdx.x;
  const unsigned w = (unsigned)(keys[b] & 0xFFFFFFFFull);
  if (threadIdx.x == 0) out[(size_t)B_ * O_ + b] = (float)w;
  const float4* src = (const float4*)(GT + (size_t)w * O_);
  float4* dst = (float4*)(out + (size_t)b * O_);
  for (int i = threadIdx.x; i < O_ / 4; i += 256) dst[i] = src[i];
}

extern "C" void kernel_launch(void* const* d_in, const int* in_sizes, int n_in,
                              void* d_out, int out_size, void* d_ws, size_t ws_size,
                              hipStream_t stream)
{
  (void)in_sizes; (void)n_in; (void)out_size; (void)ws_size;
  const float* x = (const float*)d_in[0];
  const float* kw = (const float*)d_in[1];
  const float* gw = (const float*)d_in[2];
  float* out = (float*)d_out;

  char* ws = (char*)d_ws;
  // A' 16.78MB | B' 33.55MB | xsq 16KB | wsq 32KB | keys 32KB ; GT overlays A'/B'
  __hip_bfloat16* Ap = (__hip_bfloat16*)(ws);
  __hip_bfloat16* Bp = (__hip_bfloat16*)(ws + 16777216);
  float* xsq = (float*)(ws + 50331648);
  float* wsq = (float*)(ws + 50331648 + 16384);
  unsigned long long* keys = (unsigned long long*)(ws + 50331648 + 16384 + 32768);
  float* GT = (float*)(ws);  // dead A'/B' space after GEMM

  split_all_kernel<<<B_ + H_, 256, 0, stream>>>(x, kw, Ap, Bp, xsq, wsq, keys);
  gemm_argmin_kernel<<<1024, 256, 0, stream>>>(Ap, Bp, xsq, wsq, keys);
  transposeG_kernel<<<dim3(H_ / 32, (O_ + 31) / 32), dim3(32, 8), 0, stream>>>(gw, GT);
  finalize_kernel<<<B_, 256, 0, stream>>>(keys, GT, out);
}

// Round 14
// 242.780 us; speedup vs baseline: 1.2964x; 1.2964x over previous
//
#include <hip/hip_runtime.h>
#include <hip/hip_bf16.h>

#define B_ 4096
#define D_ 1024
#define H_ 8192
#define O_ 1000
#define K2 2048          // physical packed K ([hi|lo])
#define NT 48            // logical K-tiles: 3072 / 64
#define NITER 24

typedef __attribute__((ext_vector_type(8))) short short8;
typedef __attribute__((ext_vector_type(4))) short short4v;
typedef __attribute__((ext_vector_type(4))) float f32x4;

union BF4 { __hip_bfloat16 b[4]; short4v s; };

__device__ __forceinline__ void gload16(void* ldsp, const void* g) {
  __builtin_amdgcn_global_load_lds(
      (const __attribute__((address_space(1))) unsigned int*)g,
      (__attribute__((address_space(3))) unsigned int*)ldsp, 16, 0, 0);
}

// K-tile T -> column offset in packed [hi|lo] rows. bf16x3 interleave:
// T = 3t+r: r0 = xh*wh, r1 = xl*wh, r2 = xh*wl.
__device__ __forceinline__ int aoff_(int T) {
  const int t = T / 3, r = T - 3 * t;
  return (r == 1 ? 1024 : 0) + t * 64;
}
__device__ __forceinline__ int boff_(int T) {
  const int t = T / 3, r = T - 3 * t;
  return (r == 2 ? 1024 : 0) + t * 64;
}

// ---- merged split: fp32 -> [hi|lo] bf16 + sum-of-squares + keys init ----
__global__ __launch_bounds__(256) void split_all_kernel(
    const float* __restrict__ x, const float* __restrict__ w,
    __hip_bfloat16* __restrict__ Ap, __hip_bfloat16* __restrict__ Bp,
    float* __restrict__ xsq, float* __restrict__ wsq,
    unsigned long long* __restrict__ keys)
{
  const int r = blockIdx.x;
  const int t = threadIdx.x;
  const float* src;
  __hip_bfloat16* dst;
  float* sq;
  if (r < B_) {
    src = x + (size_t)r * D_; dst = Ap + (size_t)r * K2; sq = xsq + r;
    if (t == 0) keys[r] = ~0ULL;
  } else {
    const int rr = r - B_;
    src = w + (size_t)rr * D_; dst = Bp + (size_t)rr * K2; sq = wsq + rr;
  }
  const float4 v = ((const float4*)src)[t];
  float ss = v.x * v.x + v.y * v.y + v.z * v.z + v.w * v.w;

  BF4 Hh, Ll;
  const float e[4] = {v.x, v.y, v.z, v.w};
#pragma unroll
  for (int i = 0; i < 4; ++i) {
    __hip_bfloat16 h = __float2bfloat16(e[i]);
    Hh.b[i] = h;
    Ll.b[i] = __float2bfloat16(e[i] - __bfloat162float(h));
  }
  *(short4v*)(dst + t * 4) = Hh.s;
  *(short4v*)(dst + 1024 + t * 4) = Ll.s;

#pragma unroll
  for (int o = 32; o > 0; o >>= 1) ss += __shfl_down(ss, o);
  __shared__ float wsum[4];
  if ((t & 63) == 0) wsum[t >> 6] = ss;
  __syncthreads();
  if (t == 0) *sq = (wsum[0] + wsum[1]) + (wsum[2] + wsum[3]);
}

// ---- 256x256 GEMM: literal m201 8-phase template ----
// LDS dbuf d (64KB): A0@d+0, A1@d+16K, B0@d+32K, B1@d+48K; 128B rows;
// phys 16B-unit = logical ^ (row&7) via pre-swizzled src (conflicts=0, r7/r8).
// Phase = { reads; stage 1 half; [lgkm(8) if 12 reads]; BAR; lgkm(0);
//           setprio(1); 16 MFMA; setprio(0); BAR }.
// Snake quadrants per tile: (0,0)[12 rd] (0,1)[4] (1,1)[8] (1,0)[0].
// ROLLING same-dbuf stages (half consumed last phase -> overwritten now):
//  ph0: O.A1 | ph1: (E+2).A0 | ph2: (E+2).B0 | ph3: (E+2).B1 |
//  ph4: (E+2).A1 | ph5: (O+2).A0 | ph6: (O+2).B0 | ph7: (O+2).B1
// Gates vmcnt(6) at ph3/ph7 only. Ledger (steady): at ph3-gate outstanding =
// {O.A0,B0,B1 (prev ph5-7), O.A1 (ph0), (E+2).A0,B0,B1 (ph1-3)} = 14 ->
// drains 8 oldest = ALL of tile O before ph4 reads it. At ph7-gate drains
// ALL of tile E+2 before next-iter ph0. Prologue stages 7 halves, vmcnt(6)
// drains tile0's 8. Last iter: gates vmcnt(0), stages >=NT auto-guarded.

#define BAR() do { asm volatile("" ::: "memory"); \
                   __builtin_amdgcn_s_barrier(); \
                   asm volatile("" ::: "memory"); } while (0)
#define SB0() __builtin_amdgcn_sched_barrier(0)
#define GATE_S(S) asm volatile("s_waitcnt vmcnt(" S ")" ::: "memory")
#define LGKM8() asm volatile("s_waitcnt lgkmcnt(8)" ::: "memory")
#define LGKM0() do { asm volatile("s_waitcnt lgkmcnt(0)" ::: "memory"); SB0(); } while (0)

#define DSR(dst, base, OFF) \
  asm volatile("ds_read_b128 %0, %1 offset:" OFF : "=v"(dst) : "v"(base))

// A m-half reads: F[2m+kk]; mq=0 offsets m*2048, mq=1 +16384
#define RD_A0(F, b0, b1) do { \
    DSR(F[0], b0, "0");    DSR(F[1], b1, "0"); \
    DSR(F[2], b0, "2048"); DSR(F[3], b1, "2048"); \
    DSR(F[4], b0, "4096"); DSR(F[5], b1, "4096"); \
    DSR(F[6], b0, "6144"); DSR(F[7], b1, "6144"); } while (0)
#define RD_A1(F, b0, b1) do { \
    DSR(F[0], b0, "16384"); DSR(F[1], b1, "16384"); \
    DSR(F[2], b0, "18432"); DSR(F[3], b1, "18432"); \
    DSR(F[4], b0, "20480"); DSR(F[5], b1, "20480"); \
    DSR(F[6], b0, "22528"); DSR(F[7], b1, "22528"); } while (0)
// B n-half reads: F[2n+kk]; nq=0 offsets n*2048, nq=1 +16384
#define RD_B0(F, b0, b1) do { \
    DSR(F[0], b0, "0");    DSR(F[1], b1, "0"); \
    DSR(F[2], b0, "2048"); DSR(F[3], b1, "2048"); } while (0)
#define RD_B1(F, b0, b1) do { \
    DSR(F[0], b0, "16384"); DSR(F[1], b1, "16384"); \
    DSR(F[2], b0, "18432"); DSR(F[3], b1, "18432"); } while (0)

#define STAGE(P, prow, T, isB, h) do { if ((T) < NT) { \
    const int koff_ = (isB) ? boff_(T) : aoff_(T); \
    const __hip_bfloat16* s_ = (P) + (size_t)((prow) + (h)*128 + wid*16 + srow) * K2 + koff_ + sunit * 8; \
    char* d_ = lds + ((T)&1)*65536 + (isB)*32768 + (h)*16384 + wid*2048 + lane*16; \
    gload16(d_, s_); gload16(d_ + 1024, s_ + 8*K2); } } while (0)

#define MM(mq, nq, AF, BF) do { \
    __builtin_amdgcn_s_setprio(1); \
    _Pragma("unroll") for (int m_ = 0; m_ < 4; ++m_) \
    _Pragma("unroll") for (int n_ = 0; n_ < 2; ++n_) \
    _Pragma("unroll") for (int kk = 0; kk < 2; ++kk) \
      acc[(mq)*4+m_][(nq)*2+n_] = __builtin_amdgcn_mfma_f32_16x16x32_bf16( \
          AF[2*m_+kk], BF[2*n_+kk], acc[(mq)*4+m_][(nq)*2+n_], 0, 0, 0); \
    __builtin_amdgcn_s_setprio(0); \
    SB0(); } while (0)

// One iter = tiles E (dbuf0) + O (dbuf1), 8 phases. GS: gate count string.
#define ITER8(E, O, GS) do { \
    /* ph0: Q(0,0) tile E; 12 reads */ \
    RD_A0(af, aK0, aK1); \
    RD_B0(bf0, bK0, bK1); \
    STAGE(Ap, brow, (O), 0, 1); \
    LGKM8(); BAR(); LGKM0(); \
    MM(0, 0, af, bf0); BAR(); \
    /* ph1: Q(0,1); 4 reads */ \
    RD_B1(bf1, bK0, bK1); \
    STAGE(Ap, brow, (E) + 2, 0, 0); \
    BAR(); LGKM0(); \
    MM(0, 1, af, bf1); BAR(); \
    /* ph2: Q(1,1); 8 reads */ \
    RD_A1(af, aK0, aK1); \
    STAGE(Bp, bcol, (E) + 2, 1, 0); \
    BAR(); LGKM0(); \
    MM(1, 1, af, bf1); BAR(); \
    /* ph3: Q(1,0); 0 reads; GATE */ \
    STAGE(Bp, bcol, (E) + 2, 1, 1); \
    BAR(); \
    MM(1, 0, af, bf0); \
    GATE_S(GS); BAR(); \
    /* ph4: Q(0,0) tile O (dbuf1); 12 reads */ \
    RD_A0(af, aK0d, aK1d); \
    RD_B0(bf0, bK0d, bK1d); \
    STAGE(Ap, brow, (E) + 2, 0, 1); \
    LGKM8(); BAR(); LGKM0(); \
    MM(0, 0, af, bf0); BAR(); \
    /* ph5: Q(0,1) */ \
    RD_B1(bf1, bK0d, bK1d); \
    STAGE(Ap, brow, (O) + 2, 0, 0); \
    BAR(); LGKM0(); \
    MM(0, 1, af, bf1); BAR(); \
    /* ph6: Q(1,1) */ \
    RD_A1(af, aK0d, aK1d); \
    STAGE(Bp, bcol, (O) + 2, 1, 0); \
    BAR(); LGKM0(); \
    MM(1, 1, af, bf1); BAR(); \
    /* ph7: Q(1,0); GATE */ \
    STAGE(Bp, bcol, (O) + 2, 1, 1); \
    BAR(); \
    MM(1, 0, af, bf0); \
    GATE_S(GS); BAR(); \
  } while (0)

__global__ __launch_bounds__(512, 2) void gemm_argmin_kernel(
    const __hip_bfloat16* __restrict__ Ap, const __hip_bfloat16* __restrict__ Bp,
    const float* __restrict__ xsq, const float* __restrict__ wsq,
    unsigned long long* __restrict__ keys)
{
  __shared__ char lds[131072];

  const int t = threadIdx.x;
  // XCD-aware: square 8x8 tile-chunk per XCD (r4-proven).
  const int id = blockIdx.x;
  const int xcd = id & 7;
  const int r_ = id >> 3;
  const int by = (xcd >> 2) * 8 + (r_ >> 3);
  const int bx = (xcd & 3) * 8 + (r_ & 7);
  const int brow = by * 256, bcol = bx * 256;

  const int lane = t & 63, wid = t >> 6;   // 8 waves
  const int wm = wid >> 2, wn = wid & 3;   // 2M x 4N
  const int cc = lane & 15, q = lane >> 4, sw = lane & 7;
  const unsigned kof0 = (unsigned)((q ^ sw) * 16);
  const unsigned kof1 = (unsigned)(((4 + q) ^ sw) * 16);

  const int srow = lane >> 3;
  const int sunit = (lane & 7) ^ srow;

  // asm ds_read base regs (dbuf0 / dbuf1)
  const unsigned lb = (unsigned)(uintptr_t)lds;
  const unsigned aK0 = lb + (unsigned)((wm * 64 + cc) * 128) + kof0;
  const unsigned aK1 = lb + (unsigned)((wm * 64 + cc) * 128) + kof1;
  const unsigned aK0d = aK0 + 65536, aK1d = aK1 + 65536;
  const unsigned bK0 = lb + 32768u + (unsigned)((wn * 32 + cc) * 128) + kof0;
  const unsigned bK1 = lb + 32768u + (unsigned)((wn * 32 + cc) * 128) + kof1;
  const unsigned bK0d = bK0 + 65536, bK1d = bK1 + 65536;

  f32x4 acc[8][4] = {};
  short8 af[8], bf0[4], bf1[4];

  // Prologue: 7 halves (T0 all, T1.A0/B0/B1) -> 14 loads; vmcnt(6) drains T0.
  STAGE(Ap, brow, 0, 0, 0);
  STAGE(Bp, bcol, 0, 1, 0);
  STAGE(Bp, bcol, 0, 1, 1);
  STAGE(Ap, brow, 0, 0, 1);
  STAGE(Ap, brow, 1, 0, 0);
  STAGE(Bp, bcol, 1, 1, 0);
  STAGE(Bp, bcol, 1, 1, 1);
  GATE_S("6");
  BAR();

  for (int it = 0; it < NITER - 1; ++it) {
    ITER8(2 * it, 2 * it + 1, "6");
  }
  ITER8(NT - 2, NT - 1, "0");   // last iter: drain gates; stages auto-guarded

  // Epilogue: s = (x_sq - 2*dot) + w_sq (reference fp32 rounding order).
  // C/D 16x16x32: col = lane&15, row = (lane>>4)*4 + reg.
  // row = brow + mq*128 + wm*64 + m_*16 + q*4 + r
  // col = bcol + nq*128 + wn*32 + n_*16 + cc        (r6/r7/r8-verified)
#pragma unroll
  for (int i = 0; i < 8; ++i) {
    const int mh = i >> 2, m_ = i & 3;
#pragma unroll
    for (int r = 0; r < 4; ++r) {
      const int row = brow + mh * 128 + wm * 64 + m_ * 16 + q * 4 + r;
      const float xs = xsq[row];
      unsigned long long best = ~0ULL;
#pragma unroll
      for (int j = 0; j < 4; ++j) {
        const int nh = j >> 1, n_ = j & 1;
        const int col = bcol + nh * 128 + wn * 32 + n_ * 16 + cc;
        const float s = (xs - 2.0f * acc[i][j][r]) + wsq[col];
        unsigned ub = __float_as_uint(s);
        ub = (ub & 0x80000000u) ? ~ub : (ub | 0x80000000u);
        const unsigned long long key =
            ((unsigned long long)ub << 32) | (unsigned)col;
        if (key < best) best = key;
      }
#pragma unroll
      for (int o = 1; o < 16; o <<= 1) {
        const unsigned long long v = __shfl_xor(best, o);
        if (v < best) best = v;
      }
      if (cc == 0) atomicMin(&keys[row], best);
    }
  }
}

// ---- transpose G [O,H] -> GT [H,O] ----
__global__ __launch_bounds__(256) void transposeG_kernel(
    const float* __restrict__ G, float* __restrict__ GT)
{
  __shared__ float tile[32][33];
  const int h0 = blockIdx.x * 32;
  const int o0 = blockIdx.y * 32;
  const int tx = threadIdx.x;
  const int ty = threadIdx.y;
#pragma unroll
  for (int j = 0; j < 4; ++j) {
    const int o = o0 + ty + j * 8;
    if (o < O_) tile[ty + j * 8][tx] = G[(size_t)o * H_ + h0 + tx];
  }
  __syncthreads();
  const int o = o0 + tx;
  if (o < O_) {
#pragma unroll
    for (int j = 0; j < 4; ++j)
      GT[(size_t)(h0 + ty + j * 8) * O_ + o] = tile[tx][ty + j * 8];
  }
}

// ---- winners + row gather ----
__global__ __launch_bounds__(256) void finalize_kernel(
    const unsigned long long* __restrict__ keys,
    const float* __restrict__ GT, float* __restrict__ out)
{
  const int b = blockIdx.x;
  const unsigned w = (unsigned)(keys[b] & 0xFFFFFFFFull);
  if (threadIdx.x == 0) out[(size_t)B_ * O_ + b] = (float)w;
  const float4* src = (const float4*)(GT + (size_t)w * O_);
  float4* dst = (float4*)(out + (size_t)b * O_);
  for (int i = threadIdx.x; i < O_ / 4; i += 256) dst[i] = src[i];
}

extern "C" void kernel_launch(void* const* d_in, const int* in_sizes, int n_in,
                              void* d_out, int out_size, void* d_ws, size_t ws_size,
                              hipStream_t stream)
{
  (void)in_sizes; (void)n_in; (void)out_size; (void)ws_size;
  const float* x = (const float*)d_in[0];
  const float* kw = (const float*)d_in[1];
  const float* gw = (const float*)d_in[2];
  float* out = (float*)d_out;

  char* ws = (char*)d_ws;
  // A' 16.78MB | B' 33.55MB | xsq 16KB | wsq 32KB | keys 32KB ; GT overlays A'/B'
  __hip_bfloat16* Ap = (__hip_bfloat16*)(ws);
  __hip_bfloat16* Bp = (__hip_bfloat16*)(ws + 16777216);
  float* xsq = (float*)(ws + 50331648);
  float* wsq = (float*)(ws + 50331648 + 16384);
  unsigned long long* keys = (unsigned long long*)(ws + 50331648 + 16384 + 32768);
  float* GT = (float*)(ws);  // dead A'/B' space after GEMM

  split_all_kernel<<<B_ + H_, 256, 0, stream>>>(x, kw, Ap, Bp, xsq, wsq, keys);
  gemm_argmin_kernel<<<512, 512, 0, stream>>>(Ap, Bp, xsq, wsq, keys);
  transposeG_kernel<<<dim3(H_ / 32, (O_ + 31) / 32), dim3(32, 8), 0, stream>>>(gw, GT);
  finalize_kernel<<<B_, 256, 0, stream>>>(keys, GT, out);
}